// Round 8
// baseline (229.557 us; speedup 1.0000x reference)
//
#include <hip/hip_runtime.h>
#include <hip/hip_bf16.h>

// N=8192, D_IN=128, H=64, C=40, E=262144, TAU=0.25, T=4 -> 16 steps.
constexpr int N_   = 8192;
constexpr int DIN_ = 128;
constexpr int H_   = 64;
constexpr int C_   = 40;
constexpr int STEPS_ = 16;
#define TAU_ 0.25f

typedef float f32x4 __attribute__((ext_vector_type(4)));

// ---------------- fused front-end: enc + kq + z0 = x0 @ dec_w ---------------
__global__ __launch_bounds__(256) void front_k(const float* __restrict__ xin,
    const float* __restrict__ ew, const float* __restrict__ eb,
    const float* __restrict__ wk, const float* __restrict__ kb,
    const float* __restrict__ wq, const float* __restrict__ qb,
    const float* __restrict__ dw,
    float* __restrict__ kx, float* __restrict__ qx, float* __restrict__ z0)
{
    __shared__ float xs[16][64];                 // 4 waves x 4 rows
    int wloc = threadIdx.x >> 6;
    int lane = threadIdx.x & 63;
    int r0   = (blockIdx.x * 4 + wloc) * 4;

    const float* xr = xin + (size_t)r0 * DIN_;
    float bv = eb[lane];
    float a0 = bv, a1 = bv, a2 = bv, a3 = bv;
    for (int k = 0; k < DIN_; ++k) {
        float wv = ew[k * H_ + lane];
        a0 = fmaf(xr[k],            wv, a0);
        a1 = fmaf(xr[DIN_ + k],     wv, a1);
        a2 = fmaf(xr[2 * DIN_ + k], wv, a2);
        a3 = fmaf(xr[3 * DIN_ + k], wv, a3);
    }
    float* xls = &xs[wloc * 4][0];
    xls[lane] = a0; xls[64 + lane] = a1; xls[128 + lane] = a2; xls[192 + lane] = a3;

    float kbv = kb[lane], qbv = qb[lane];
    float ak0 = kbv, ak1 = kbv, ak2 = kbv, ak3 = kbv;
    float aq0 = qbv, aq1 = qbv, aq2 = qbv, aq3 = qbv;
    for (int k = 0; k < H_; ++k) {
        float wkv = wk[k * H_ + lane];
        float wqv = wq[k * H_ + lane];
        float x0v = xls[k], x1v = xls[64 + k], x2v = xls[128 + k], x3v = xls[192 + k];
        ak0 = fmaf(x0v, wkv, ak0);  aq0 = fmaf(x0v, wqv, aq0);
        ak1 = fmaf(x1v, wkv, ak1);  aq1 = fmaf(x1v, wqv, aq1);
        ak2 = fmaf(x2v, wkv, ak2);  aq2 = fmaf(x2v, wqv, aq2);
        ak3 = fmaf(x3v, wkv, ak3);  aq3 = fmaf(x3v, wqv, aq3);
    }
    float* ok = kx + (size_t)r0 * H_ + lane;
    float* oq = qx + (size_t)r0 * H_ + lane;
    ok[0] = ak0; ok[H_] = ak1; ok[2 * H_] = ak2; ok[3 * H_] = ak3;
    oq[0] = aq0; oq[H_] = aq1; oq[2 * H_] = aq2; oq[3 * H_] = aq3;

    if (lane < C_) {
        float z0a = 0.f, z1a = 0.f, z2a = 0.f, z3a = 0.f;
        for (int k = 0; k < H_; ++k) {
            float dv = dw[k * C_ + lane];
            z0a = fmaf(xls[k],       dv, z0a);
            z1a = fmaf(xls[64 + k],  dv, z1a);
            z2a = fmaf(xls[128 + k], dv, z2a);
            z3a = fmaf(xls[192 + k], dv, z3a);
        }
        z0[(size_t)r0 * C_ + lane]       = z0a;
        z0[(size_t)(r0 + 1) * C_ + lane] = z1a;
        z0[(size_t)(r0 + 2) * C_ + lane] = z2a;
        z0[(size_t)(r0 + 3) * C_ + lane] = z3a;
    }
}

// ---------------- edge pipeline ----------------

__global__ __launch_bounds__(256) void count_k(const int2* __restrict__ edges,
    int* __restrict__ deg, int E)
{
    int e = blockIdx.x * 256 + threadIdx.x;
    if (e >= E) return;
    atomicAdd(&deg[edges[e].x], 1);
}

__global__ __launch_bounds__(256) void scan_k(const int* __restrict__ deg,
    int* __restrict__ row_ptr, int* __restrict__ row_fill)
{
    __shared__ int partial[257];
    int t = threadIdx.x;
    const int chunk = N_ / 256;
    int base = t * chunk;
    int s = 0;
    for (int i = 0; i < chunk; ++i) s += deg[base + i];
    partial[t] = s;
    __syncthreads();
    if (t == 0) {
        int run = 0;
        for (int i = 0; i < 256; ++i) { int tmp = partial[i]; partial[i] = run; run += tmp; }
        partial[256] = run;
    }
    __syncthreads();
    int run = partial[t];
    for (int i = 0; i < chunk; ++i) {
        row_ptr[base + i] = run;
        row_fill[base + i] = run;
        run += deg[base + i];
    }
    if (t == 255) row_ptr[N_] = run;
}

// 8 lanes per edge: each lane reads 2 float4s of kx-row and qx-row; 3-shfl
// reduce; lane 0 places (v, exp(dot/H)).
__global__ __launch_bounds__(256) void score_place_k(const int2* __restrict__ edges,
    const float* __restrict__ kx, const float* __restrict__ qx,
    int* __restrict__ row_fill, int* __restrict__ csr_v, float* __restrict__ csr_w, int E)
{
    int t  = blockIdx.x * 256 + threadIdx.x;
    int eg = t >> 3;
    int sl = t & 7;
    if (eg >= E) return;
    int2 uv = edges[eg];
    const float4* kr = (const float4*)(kx + (size_t)uv.x * H_);
    const float4* qr = (const float4*)(qx + (size_t)uv.y * H_);
    float4 a0 = kr[sl], a1 = kr[sl + 8];
    float4 b0 = qr[sl], b1 = qr[sl + 8];
    float d = a0.x * b0.x + a0.y * b0.y + a0.z * b0.z + a0.w * b0.w
            + a1.x * b1.x + a1.y * b1.y + a1.z * b1.z + a1.w * b1.w;
    d += __shfl_xor(d, 1);
    d += __shfl_xor(d, 2);
    d += __shfl_xor(d, 4);
    if (sl == 0) {
        float w = expf(d * (1.0f / (float)H_));
        int pos = atomicAdd(&row_fill[uv.x], 1);
        csr_v[pos] = uv.y;
        csr_w[pos] = w;
    }
}

__global__ __launch_bounds__(256) void dedup_k(const int* __restrict__ row_ptr,
    const int* __restrict__ csr_v, const float* __restrict__ csr_w,
    int2* __restrict__ vw)
{
    __shared__ unsigned int bm[4][256];   // 8192 bits per wave
    int wv   = threadIdx.x >> 6;
    int lane = threadIdx.x & 63;
    int row  = blockIdx.x * 4 + wv;
    unsigned int* b = bm[wv];
    for (int i = lane; i < 256; i += 64) b[i] = 0;
    __syncthreads();
    int p0 = row_ptr[row], p1 = row_ptr[row + 1];
    float wsum = 0.f;
    for (int p = p0 + lane; p < p1; p += 64) {
        int v = csr_v[p];
        unsigned int m = 1u << (v & 31);
        unsigned int old = atomicOr(&b[v >> 5], m);
        float w = (old & m) ? 0.0f : csr_w[p];
        vw[p] = make_int2(v, __float_as_int(w));
        wsum += w;
    }
    #pragma unroll
    for (int off = 1; off < 64; off <<= 1) wsum += __shfl_xor(wsum, off);
    if (p0 == p1) return;
    float scale = TAU_ / wsum;
    for (int p = p0 + lane; p < p1; p += 64) {
        int2 e = vw[p];
        e.y = __float_as_int(__int_as_float(e.y) * scale);
        vw[p] = e;
    }
}

// ---------------- propagation step over z (N x 40) ----------------
// Wave = row. Lane L: edge-group grp=L>>4, float4-col c=L&15 (c<10 valid).
// 32-edge superchunk: 8 conditional int2 loads then 8 independent dwordx4
// gathers in flight (avg row deg=32 -> typically ONE iteration).
template <bool LAST>
__global__ __launch_bounds__(256) void stepz_k(const float* __restrict__ zin,
    float* __restrict__ zout, const int* __restrict__ row_ptr,
    const int2* __restrict__ vw, const float* __restrict__ db)
{
    int row  = (blockIdx.x * 256 + threadIdx.x) >> 6;
    int lane = threadIdx.x & 63;
    int grp  = lane >> 4;
    int col4 = lane & 15;
    int c9   = (col4 < 10) ? col4 : 9;
    int coff = c9 << 2;
    int p0 = row_ptr[row], p1 = row_ptr[row + 1];
    f32x4 acc = {0.f, 0.f, 0.f, 0.f};
    for (int base = p0; base < p1; base += 32) {
        int i = base + grp;
        int2 e0 = (i      < p1) ? vw[i]      : make_int2(0, 0);
        int2 e1 = (i + 4  < p1) ? vw[i + 4]  : make_int2(0, 0);
        int2 e2 = (i + 8  < p1) ? vw[i + 8]  : make_int2(0, 0);
        int2 e3 = (i + 12 < p1) ? vw[i + 12] : make_int2(0, 0);
        int2 e4 = (i + 16 < p1) ? vw[i + 16] : make_int2(0, 0);
        int2 e5 = (i + 20 < p1) ? vw[i + 20] : make_int2(0, 0);
        int2 e6 = (i + 24 < p1) ? vw[i + 24] : make_int2(0, 0);
        int2 e7 = (i + 28 < p1) ? vw[i + 28] : make_int2(0, 0);
        f32x4 g0 = *(const f32x4*)(zin + (size_t)e0.x * C_ + coff);
        f32x4 g1 = *(const f32x4*)(zin + (size_t)e1.x * C_ + coff);
        f32x4 g2 = *(const f32x4*)(zin + (size_t)e2.x * C_ + coff);
        f32x4 g3 = *(const f32x4*)(zin + (size_t)e3.x * C_ + coff);
        f32x4 g4 = *(const f32x4*)(zin + (size_t)e4.x * C_ + coff);
        f32x4 g5 = *(const f32x4*)(zin + (size_t)e5.x * C_ + coff);
        f32x4 g6 = *(const f32x4*)(zin + (size_t)e6.x * C_ + coff);
        f32x4 g7 = *(const f32x4*)(zin + (size_t)e7.x * C_ + coff);
        float w0 = __int_as_float(e0.y), w1 = __int_as_float(e1.y);
        float w2 = __int_as_float(e2.y), w3 = __int_as_float(e3.y);
        float w4 = __int_as_float(e4.y), w5 = __int_as_float(e5.y);
        float w6 = __int_as_float(e6.y), w7 = __int_as_float(e7.y);
        #define FMA4_(w, g) do { \
            acc[0] = fmaf((w), (g)[0], acc[0]); acc[1] = fmaf((w), (g)[1], acc[1]); \
            acc[2] = fmaf((w), (g)[2], acc[2]); acc[3] = fmaf((w), (g)[3], acc[3]); } while (0)
        FMA4_(w0, g0); FMA4_(w1, g1); FMA4_(w2, g2); FMA4_(w3, g3);
        FMA4_(w4, g4); FMA4_(w5, g5); FMA4_(w6, g6); FMA4_(w7, g7);
        #undef FMA4_
    }
    acc[0] += __shfl_xor(acc[0], 16); acc[1] += __shfl_xor(acc[1], 16);
    acc[2] += __shfl_xor(acc[2], 16); acc[3] += __shfl_xor(acc[3], 16);
    acc[0] += __shfl_xor(acc[0], 32); acc[1] += __shfl_xor(acc[1], 32);
    acc[2] += __shfl_xor(acc[2], 32); acc[3] += __shfl_xor(acc[3], 32);
    if (grp == 0 && col4 < 10) {
        f32x4 xr = *(const f32x4*)(zin + (size_t)row * C_ + (col4 << 2));
        f32x4 r;
        r[0] = fmaf(1.0f - TAU_, xr[0], acc[0]);
        r[1] = fmaf(1.0f - TAU_, xr[1], acc[1]);
        r[2] = fmaf(1.0f - TAU_, xr[2], acc[2]);
        r[3] = fmaf(1.0f - TAU_, xr[3], acc[3]);
        if (LAST) {
            f32x4 bb = *(const f32x4*)(db + (col4 << 2));
            r[0] += bb[0]; r[1] += bb[1]; r[2] += bb[2]; r[3] += bb[3];
        }
        *(f32x4*)(zout + (size_t)row * C_ + (col4 << 2)) = r;
    }
}

extern "C" void kernel_launch(void* const* d_in, const int* in_sizes, int n_in,
                              void* d_out, int out_size, void* d_ws, size_t ws_size,
                              hipStream_t stream)
{
    const float* x_in  = (const float*)d_in[0];
    const float* enc_w = (const float*)d_in[1];
    const float* enc_b = (const float*)d_in[2];
    const float* wk_w  = (const float*)d_in[3];
    const float* wk_b  = (const float*)d_in[4];
    const float* wq_w  = (const float*)d_in[5];
    const float* wq_b  = (const float*)d_in[6];
    const float* dec_w = (const float*)d_in[7];
    const float* dec_b = (const float*)d_in[8];
    const int2*  edges = (const int2*)d_in[9];
    const int E = in_sizes[9] / 2;   // 262144
    float* out = (float*)d_out;

    char* ws = (char*)d_ws;
    float* za       = (float*)(ws + 0);                           // 1.25 MB + pad
    float* zb       = (float*)(ws + (2u << 20));                  // 1.25 MB + pad
    float* kx       = (float*)(ws + (4u << 20));                  // 2 MB
    float* qx       = (float*)(ws + (6u << 20));                  // 2 MB
    int*   csr_v    = (int*)  (ws + (8u << 20));                  // 1 MB
    float* csr_w    = (float*)(ws + (9u << 20));                  // 1 MB
    int2*  vw       = (int2*) (ws + (10u << 20));                 // 2 MB
    int*   deg      = (int*)  (ws + (12u << 20));                 // 32 KB
    int*   row_ptr  = (int*)  (ws + (12u << 20) + (64u << 10));   // 32 KB + 4
    int*   row_fill = (int*)  (ws + (12u << 20) + (128u << 10));  // 32 KB

    hipMemsetAsync(deg, 0, N_ * sizeof(int), stream);

    front_k<<<N_ / 16, 256, 0, stream>>>(x_in, enc_w, enc_b, wk_w, wk_b,
                                         wq_w, wq_b, dec_w, kx, qx, za);
    count_k<<<(E + 255) / 256, 256, 0, stream>>>(edges, deg, E);
    scan_k<<<1, 256, 0, stream>>>(deg, row_ptr, row_fill);
    score_place_k<<<(E * 8 + 255) / 256, 256, 0, stream>>>(edges, kx, qx, row_fill, csr_v, csr_w, E);
    dedup_k<<<N_ / 4, 256, 0, stream>>>(row_ptr, csr_v, csr_w, vw);

    float* zi = za;
    for (int s = 0; s < STEPS_ - 1; ++s) {
        stepz_k<false><<<N_ / 4, 256, 0, stream>>>(zi, (zi == za) ? zb : za,
                                                   row_ptr, vw, dec_b);
        zi = (zi == za) ? zb : za;
    }
    stepz_k<true><<<N_ / 4, 256, 0, stream>>>(zi, out, row_ptr, vw, dec_b);
}

// Round 9
// 188.142 us; speedup vs baseline: 1.2201x; 1.2201x over previous
//
#include <hip/hip_runtime.h>
#include <hip/hip_bf16.h>

// N=8192, D_IN=128, H=64, C=40, E=262144, TAU=0.25, T=4 -> 16 steps.
constexpr int N_   = 8192;
constexpr int DIN_ = 128;
constexpr int H_   = 64;
constexpr int C_   = 40;
constexpr int STEPS_ = 16;
constexpr int CAP_ = 128;            // padded row bucket capacity (max raw deg ~65)
#define TAU_ 0.25f

typedef float f32x4 __attribute__((ext_vector_type(4)));

// ---------------- fused front-end: enc + kq + z0 = x0 @ dec_w ---------------
__global__ __launch_bounds__(256) void front_k(const float* __restrict__ xin,
    const float* __restrict__ ew, const float* __restrict__ eb,
    const float* __restrict__ wk, const float* __restrict__ kb,
    const float* __restrict__ wq, const float* __restrict__ qb,
    const float* __restrict__ dw,
    float* __restrict__ kx, float* __restrict__ qx, float* __restrict__ z0)
{
    __shared__ float xs[16][64];                 // 4 waves x 4 rows
    int wloc = threadIdx.x >> 6;
    int lane = threadIdx.x & 63;
    int r0   = (blockIdx.x * 4 + wloc) * 4;

    const float* xr = xin + (size_t)r0 * DIN_;
    float bv = eb[lane];
    float a0 = bv, a1 = bv, a2 = bv, a3 = bv;
    for (int k = 0; k < DIN_; ++k) {
        float wv = ew[k * H_ + lane];
        a0 = fmaf(xr[k],            wv, a0);
        a1 = fmaf(xr[DIN_ + k],     wv, a1);
        a2 = fmaf(xr[2 * DIN_ + k], wv, a2);
        a3 = fmaf(xr[3 * DIN_ + k], wv, a3);
    }
    float* xls = &xs[wloc * 4][0];
    xls[lane] = a0; xls[64 + lane] = a1; xls[128 + lane] = a2; xls[192 + lane] = a3;

    float kbv = kb[lane], qbv = qb[lane];
    float ak0 = kbv, ak1 = kbv, ak2 = kbv, ak3 = kbv;
    float aq0 = qbv, aq1 = qbv, aq2 = qbv, aq3 = qbv;
    for (int k = 0; k < H_; ++k) {
        float wkv = wk[k * H_ + lane];
        float wqv = wq[k * H_ + lane];
        float x0v = xls[k], x1v = xls[64 + k], x2v = xls[128 + k], x3v = xls[192 + k];
        ak0 = fmaf(x0v, wkv, ak0);  aq0 = fmaf(x0v, wqv, aq0);
        ak1 = fmaf(x1v, wkv, ak1);  aq1 = fmaf(x1v, wqv, aq1);
        ak2 = fmaf(x2v, wkv, ak2);  aq2 = fmaf(x2v, wqv, aq2);
        ak3 = fmaf(x3v, wkv, ak3);  aq3 = fmaf(x3v, wqv, aq3);
    }
    float* ok = kx + (size_t)r0 * H_ + lane;
    float* oq = qx + (size_t)r0 * H_ + lane;
    ok[0] = ak0; ok[H_] = ak1; ok[2 * H_] = ak2; ok[3 * H_] = ak3;
    oq[0] = aq0; oq[H_] = aq1; oq[2 * H_] = aq2; oq[3 * H_] = aq3;

    if (lane < C_) {
        float z0a = 0.f, z1a = 0.f, z2a = 0.f, z3a = 0.f;
        for (int k = 0; k < H_; ++k) {
            float dv = dw[k * C_ + lane];
            z0a = fmaf(xls[k],       dv, z0a);
            z1a = fmaf(xls[64 + k],  dv, z1a);
            z2a = fmaf(xls[128 + k], dv, z2a);
            z3a = fmaf(xls[192 + k], dv, z3a);
        }
        z0[(size_t)r0 * C_ + lane]       = z0a;
        z0[(size_t)(r0 + 1) * C_ + lane] = z1a;
        z0[(size_t)(r0 + 2) * C_ + lane] = z2a;
        z0[(size_t)(r0 + 3) * C_ + lane] = z3a;
    }
}

// ---------------- edge scoring straight into padded row buckets -------------
// 8 lanes per edge; lane 0 scatters (v, w=exp(dot/H)) to bvw[u*CAP + slot].
__global__ __launch_bounds__(256) void score_place_k(const int2* __restrict__ edges,
    const float* __restrict__ kx, const float* __restrict__ qx,
    int* __restrict__ fill, int2* __restrict__ bvw, int E)
{
    int t  = blockIdx.x * 256 + threadIdx.x;
    int eg = t >> 3;
    int sl = t & 7;
    if (eg >= E) return;
    int2 uv = edges[eg];
    const float4* kr = (const float4*)(kx + (size_t)uv.x * H_);
    const float4* qr = (const float4*)(qx + (size_t)uv.y * H_);
    float4 a0 = kr[sl], a1 = kr[sl + 8];
    float4 b0 = qr[sl], b1 = qr[sl + 8];
    float d = a0.x * b0.x + a0.y * b0.y + a0.z * b0.z + a0.w * b0.w
            + a1.x * b1.x + a1.y * b1.y + a1.z * b1.z + a1.w * b1.w;
    d += __shfl_xor(d, 1);
    d += __shfl_xor(d, 2);
    d += __shfl_xor(d, 4);
    if (sl == 0) {
        float w = expf(d * (1.0f / (float)H_));
        int pos = atomicAdd(&fill[uv.x], 1);
        if (pos < CAP_)
            bvw[(size_t)uv.x * CAP_ + pos] = make_int2(uv.y, __float_as_int(w));
    }
}

// ---------------- per-row dedup + normalize + pad to 16 ----------------
// Wave per row. LDS bitmap dedup (any-winner exact: dup weights identical).
// Writes vwp[row*CAP + i] with dups/padding carrying w=0; nc[row]=#16-chunks.
__global__ __launch_bounds__(256) void dedup_k(const int* __restrict__ fill,
    const int2* __restrict__ bvw, int2* __restrict__ vwp, int* __restrict__ nc)
{
    __shared__ unsigned int bm[4][256];   // 8192 bits per wave
    int wv   = threadIdx.x >> 6;
    int lane = threadIdx.x & 63;
    int row  = blockIdx.x * 4 + wv;
    unsigned int* b = bm[wv];
    for (int i = lane; i < 256; i += 64) b[i] = 0;
    __syncthreads();
    int f = fill[row];
    if (f > CAP_) f = CAP_;
    int padded = (f + 15) & ~15;
    size_t base = (size_t)row * CAP_;
    float wsum = 0.f;
    for (int p = lane; p < padded; p += 64) {
        int2 e = make_int2(0, 0);
        float w = 0.f;
        if (p < f) {
            e = bvw[base + p];
            unsigned int m = 1u << (e.x & 31);
            unsigned int old = atomicOr(&b[e.x >> 5], m);
            w = (old & m) ? 0.0f : __int_as_float(e.y);
        }
        vwp[base + p] = make_int2(e.x, __float_as_int(w));
        wsum += w;
    }
    #pragma unroll
    for (int off = 1; off < 64; off <<= 1) wsum += __shfl_xor(wsum, off);
    if (lane == 0) nc[row] = padded >> 4;
    if (f == 0) return;
    float scale = TAU_ / wsum;
    for (int p = lane; p < f; p += 64) {
        int2 e = vwp[base + p];
        e.y = __float_as_int(__int_as_float(e.y) * scale);
        vwp[base + p] = e;
    }
}

// ---------------- propagation step over z (N x 40) ----------------
// Wave = row. Lane L: edge-group grp=L>>4, float4-col c=L&15 (c<10 valid,
// c>=10 clamps to col 9 -> coalesces away). Branch-free 16-edge chunks
// (padding has w=0). Row stride CAP*8B = 1 KB, cache-line aligned.
template <bool LAST>
__global__ __launch_bounds__(256) void stepz_k(const float* __restrict__ zin,
    float* __restrict__ zout, const int* __restrict__ nc,
    const int2* __restrict__ vwp, const float* __restrict__ db)
{
    int row  = (blockIdx.x * 256 + threadIdx.x) >> 6;
    int lane = threadIdx.x & 63;
    int grp  = lane >> 4;
    int col4 = lane & 15;
    int c9   = (col4 < 10) ? col4 : 9;
    int coff = c9 << 2;
    int ncv  = nc[row];                    // wave-uniform
    size_t base = (size_t)row * CAP_ + grp;
    f32x4 acc = {0.f, 0.f, 0.f, 0.f};
    for (int c = 0; c < ncv; ++c) {
        size_t i = base + c * 16;
        int2 e0 = vwp[i];
        int2 e1 = vwp[i + 4];
        int2 e2 = vwp[i + 8];
        int2 e3 = vwp[i + 12];
        f32x4 g0 = *(const f32x4*)(zin + (size_t)e0.x * C_ + coff);
        f32x4 g1 = *(const f32x4*)(zin + (size_t)e1.x * C_ + coff);
        f32x4 g2 = *(const f32x4*)(zin + (size_t)e2.x * C_ + coff);
        f32x4 g3 = *(const f32x4*)(zin + (size_t)e3.x * C_ + coff);
        float w0 = __int_as_float(e0.y), w1 = __int_as_float(e1.y);
        float w2 = __int_as_float(e2.y), w3 = __int_as_float(e3.y);
        acc[0] = fmaf(w0, g0[0], acc[0]); acc[1] = fmaf(w0, g0[1], acc[1]);
        acc[2] = fmaf(w0, g0[2], acc[2]); acc[3] = fmaf(w0, g0[3], acc[3]);
        acc[0] = fmaf(w1, g1[0], acc[0]); acc[1] = fmaf(w1, g1[1], acc[1]);
        acc[2] = fmaf(w1, g1[2], acc[2]); acc[3] = fmaf(w1, g1[3], acc[3]);
        acc[0] = fmaf(w2, g2[0], acc[0]); acc[1] = fmaf(w2, g2[1], acc[1]);
        acc[2] = fmaf(w2, g2[2], acc[2]); acc[3] = fmaf(w2, g2[3], acc[3]);
        acc[0] = fmaf(w3, g3[0], acc[0]); acc[1] = fmaf(w3, g3[1], acc[1]);
        acc[2] = fmaf(w3, g3[2], acc[2]); acc[3] = fmaf(w3, g3[3], acc[3]);
    }
    acc[0] += __shfl_xor(acc[0], 16); acc[1] += __shfl_xor(acc[1], 16);
    acc[2] += __shfl_xor(acc[2], 16); acc[3] += __shfl_xor(acc[3], 16);
    acc[0] += __shfl_xor(acc[0], 32); acc[1] += __shfl_xor(acc[1], 32);
    acc[2] += __shfl_xor(acc[2], 32); acc[3] += __shfl_xor(acc[3], 32);
    if (grp == 0 && col4 < 10) {
        f32x4 xr = *(const f32x4*)(zin + (size_t)row * C_ + (col4 << 2));
        f32x4 r;
        r[0] = fmaf(1.0f - TAU_, xr[0], acc[0]);
        r[1] = fmaf(1.0f - TAU_, xr[1], acc[1]);
        r[2] = fmaf(1.0f - TAU_, xr[2], acc[2]);
        r[3] = fmaf(1.0f - TAU_, xr[3], acc[3]);
        if (LAST) {
            f32x4 bb = *(const f32x4*)(db + (col4 << 2));
            r[0] += bb[0]; r[1] += bb[1]; r[2] += bb[2]; r[3] += bb[3];
        }
        *(f32x4*)(zout + (size_t)row * C_ + (col4 << 2)) = r;
    }
}

extern "C" void kernel_launch(void* const* d_in, const int* in_sizes, int n_in,
                              void* d_out, int out_size, void* d_ws, size_t ws_size,
                              hipStream_t stream)
{
    const float* x_in  = (const float*)d_in[0];
    const float* enc_w = (const float*)d_in[1];
    const float* enc_b = (const float*)d_in[2];
    const float* wk_w  = (const float*)d_in[3];
    const float* wk_b  = (const float*)d_in[4];
    const float* wq_w  = (const float*)d_in[5];
    const float* wq_b  = (const float*)d_in[6];
    const float* dec_w = (const float*)d_in[7];
    const float* dec_b = (const float*)d_in[8];
    const int2*  edges = (const int2*)d_in[9];
    const int E = in_sizes[9] / 2;   // 262144
    float* out = (float*)d_out;

    char* ws = (char*)d_ws;
    float* za   = (float*)(ws + 0);                    // 1.31 MB (+pad)
    float* zb   = (float*)(ws + (2u << 20));           // 1.31 MB (+pad)
    float* kx   = (float*)(ws + (4u << 20));           // 2 MB
    float* qx   = (float*)(ws + (6u << 20));           // 2 MB
    int2*  bvw  = (int2*) (ws + (8u << 20));           // 8 MB  raw buckets
    int2*  vwp  = (int2*) (ws + (16u << 20));          // 8 MB  deduped+padded
    int*   fill = (int*)  (ws + (24u << 20));          // 32 KB
    int*   nc   = (int*)  (ws + (24u << 20) + (64u << 10)); // 32 KB

    hipMemsetAsync(fill, 0, N_ * sizeof(int), stream);

    front_k<<<N_ / 16, 256, 0, stream>>>(x_in, enc_w, enc_b, wk_w, wk_b,
                                         wq_w, wq_b, dec_w, kx, qx, za);
    score_place_k<<<(E * 8 + 255) / 256, 256, 0, stream>>>(edges, kx, qx, fill, bvw, E);
    dedup_k<<<N_ / 4, 256, 0, stream>>>(fill, bvw, vwp, nc);

    float* zi = za;
    for (int s = 0; s < STEPS_ - 1; ++s) {
        stepz_k<false><<<N_ / 4, 256, 0, stream>>>(zi, (zi == za) ? zb : za,
                                                   nc, vwp, dec_b);
        zi = (zi == za) ? zb : za;
    }
    stepz_k<true><<<N_ / 4, 256, 0, stream>>>(zi, out, nc, vwp, dec_b);
}

// Round 10
// 166.002 us; speedup vs baseline: 1.3829x; 1.1334x over previous
//
#include <hip/hip_runtime.h>
#include <hip/hip_bf16.h>

// N=8192, D_IN=128, H=64, C=40, E=262144, TAU=0.25, T=4 -> 16 steps.
constexpr int N_   = 8192;
constexpr int DIN_ = 128;
constexpr int H_   = 64;
constexpr int C_   = 40;
constexpr int STEPS_ = 16;
constexpr int CAP_ = 128;            // row bucket capacity (max raw deg ~65)
#define TAU_ 0.25f

typedef float f32x4 __attribute__((ext_vector_type(4)));

// pack (v, w) -> 4B: high 19 bits = fp32 w RNE-rounded to 10-bit mantissa,
// low 13 bits = v. w >= 0 always; w=0 packs/decodes exactly.
__device__ __forceinline__ unsigned int packvw(int v, float w)
{
    unsigned int u = __float_as_uint(w);
    u += 0x0FFFu + ((u >> 13) & 1u);     // round-to-nearest-even at bit 13
    u &= 0xFFFFE000u;
    return u | (unsigned int)v;
}

// ---------------- fused front-end: enc + kq + z0 = x0 @ dec_w ---------------
__global__ __launch_bounds__(256) void front_k(const float* __restrict__ xin,
    const float* __restrict__ ew, const float* __restrict__ eb,
    const float* __restrict__ wk, const float* __restrict__ kb,
    const float* __restrict__ wq, const float* __restrict__ qb,
    const float* __restrict__ dw,
    float* __restrict__ kx, float* __restrict__ qx, float* __restrict__ z0)
{
    __shared__ float xs[16][64];                 // 4 waves x 4 rows
    int wloc = threadIdx.x >> 6;
    int lane = threadIdx.x & 63;
    int r0   = (blockIdx.x * 4 + wloc) * 4;

    const float* xr = xin + (size_t)r0 * DIN_;
    float bv = eb[lane];
    float a0 = bv, a1 = bv, a2 = bv, a3 = bv;
    for (int k = 0; k < DIN_; ++k) {
        float wv = ew[k * H_ + lane];
        a0 = fmaf(xr[k],            wv, a0);
        a1 = fmaf(xr[DIN_ + k],     wv, a1);
        a2 = fmaf(xr[2 * DIN_ + k], wv, a2);
        a3 = fmaf(xr[3 * DIN_ + k], wv, a3);
    }
    float* xls = &xs[wloc * 4][0];
    xls[lane] = a0; xls[64 + lane] = a1; xls[128 + lane] = a2; xls[192 + lane] = a3;

    float kbv = kb[lane], qbv = qb[lane];
    float ak0 = kbv, ak1 = kbv, ak2 = kbv, ak3 = kbv;
    float aq0 = qbv, aq1 = qbv, aq2 = qbv, aq3 = qbv;
    for (int k = 0; k < H_; ++k) {
        float wkv = wk[k * H_ + lane];
        float wqv = wq[k * H_ + lane];
        float x0v = xls[k], x1v = xls[64 + k], x2v = xls[128 + k], x3v = xls[192 + k];
        ak0 = fmaf(x0v, wkv, ak0);  aq0 = fmaf(x0v, wqv, aq0);
        ak1 = fmaf(x1v, wkv, ak1);  aq1 = fmaf(x1v, wqv, aq1);
        ak2 = fmaf(x2v, wkv, ak2);  aq2 = fmaf(x2v, wqv, aq2);
        ak3 = fmaf(x3v, wkv, ak3);  aq3 = fmaf(x3v, wqv, aq3);
    }
    float* ok = kx + (size_t)r0 * H_ + lane;
    float* oq = qx + (size_t)r0 * H_ + lane;
    ok[0] = ak0; ok[H_] = ak1; ok[2 * H_] = ak2; ok[3 * H_] = ak3;
    oq[0] = aq0; oq[H_] = aq1; oq[2 * H_] = aq2; oq[3 * H_] = aq3;

    if (lane < C_) {
        float z0a = 0.f, z1a = 0.f, z2a = 0.f, z3a = 0.f;
        for (int k = 0; k < H_; ++k) {
            float dv = dw[k * C_ + lane];
            z0a = fmaf(xls[k],       dv, z0a);
            z1a = fmaf(xls[64 + k],  dv, z1a);
            z2a = fmaf(xls[128 + k], dv, z2a);
            z3a = fmaf(xls[192 + k], dv, z3a);
        }
        z0[(size_t)r0 * C_ + lane]       = z0a;
        z0[(size_t)(r0 + 1) * C_ + lane] = z1a;
        z0[(size_t)(r0 + 2) * C_ + lane] = z2a;
        z0[(size_t)(r0 + 3) * C_ + lane] = z3a;
    }
}

// ---------------- edge scoring straight into padded row buckets -------------
// 8 lanes per edge; lane 0 scatters (v, w=exp(dot/H)) to bvw[u*CAP + slot].
__global__ __launch_bounds__(256) void score_place_k(const int2* __restrict__ edges,
    const float* __restrict__ kx, const float* __restrict__ qx,
    int* __restrict__ fill, int2* __restrict__ bvw, int E)
{
    int t  = blockIdx.x * 256 + threadIdx.x;
    int eg = t >> 3;
    int sl = t & 7;
    if (eg >= E) return;
    int2 uv = edges[eg];
    const float4* kr = (const float4*)(kx + (size_t)uv.x * H_);
    const float4* qr = (const float4*)(qx + (size_t)uv.y * H_);
    float4 a0 = kr[sl], a1 = kr[sl + 8];
    float4 b0 = qr[sl], b1 = qr[sl + 8];
    float d = a0.x * b0.x + a0.y * b0.y + a0.z * b0.z + a0.w * b0.w
            + a1.x * b1.x + a1.y * b1.y + a1.z * b1.z + a1.w * b1.w;
    d += __shfl_xor(d, 1);
    d += __shfl_xor(d, 2);
    d += __shfl_xor(d, 4);
    if (sl == 0) {
        float w = expf(d * (1.0f / (float)H_));
        int pos = atomicAdd(&fill[uv.x], 1);
        if (pos < CAP_)
            bvw[(size_t)uv.x * CAP_ + pos] = make_int2(uv.y, __float_as_int(w));
    }
}

// ---------------- per-row dedup + normalize + pack (single pass) ------------
// Wave per row; each lane owns slots {lane, lane+64} (CAP=128). LDS bitmap
// dedup (any-winner exact: dup weights identical; order irrelevant). Packed
// 4B (v,w) written once; padding slots pack to 0 -> w=0.
__global__ __launch_bounds__(256) void dedup_k(const int* __restrict__ fill,
    const int2* __restrict__ bvw, unsigned int* __restrict__ pw,
    int* __restrict__ nc)
{
    __shared__ unsigned int bm[4][256];   // 8192 bits per wave
    int wv   = threadIdx.x >> 6;
    int lane = threadIdx.x & 63;
    int row  = blockIdx.x * 4 + wv;
    unsigned int* b = bm[wv];
    for (int i = lane; i < 256; i += 64) b[i] = 0;
    __syncthreads();
    int f = fill[row];
    if (f > CAP_) f = CAP_;
    int padded = (f + 15) & ~15;
    size_t base = (size_t)row * CAP_;
    int2 ea = make_int2(0, 0), eb = make_int2(0, 0);
    float wa = 0.f, wb = 0.f;
    if (lane < f) {
        ea = bvw[base + lane];
        unsigned int m = 1u << (ea.x & 31);
        unsigned int old = atomicOr(&b[ea.x >> 5], m);
        wa = (old & m) ? 0.0f : __int_as_float(ea.y);
    }
    if (64 + lane < f) {
        eb = bvw[base + 64 + lane];
        unsigned int m = 1u << (eb.x & 31);
        unsigned int old = atomicOr(&b[eb.x >> 5], m);
        wb = (old & m) ? 0.0f : __int_as_float(eb.y);
    }
    float wsum = wa + wb;
    #pragma unroll
    for (int off = 1; off < 64; off <<= 1) wsum += __shfl_xor(wsum, off);
    if (lane == 0) nc[row] = padded >> 4;
    if (f == 0) return;
    float scale = TAU_ / wsum;
    if (lane < padded)      pw[base + lane]      = packvw(ea.x, wa * scale);
    if (64 + lane < padded) pw[base + 64 + lane] = packvw(eb.x, wb * scale);
}

// ---------------- propagation step over z (N x 40) ----------------
// Wave = row. Lane L: edge-group grp=L>>4, float4-col c=L&15 (c<10 valid,
// c>=10 clamps to col 9 -> coalesces away). Branch-free 16-edge chunks of
// packed 4B (v,w); padding has w=0. Row stride CAP*4B = 512B, line-aligned.
template <bool LAST>
__global__ __launch_bounds__(256) void stepz_k(const float* __restrict__ zin,
    float* __restrict__ zout, const int* __restrict__ nc,
    const unsigned int* __restrict__ pw, const float* __restrict__ db)
{
    int row  = (blockIdx.x * 256 + threadIdx.x) >> 6;
    int lane = threadIdx.x & 63;
    int grp  = lane >> 4;
    int col4 = lane & 15;
    int c9   = (col4 < 10) ? col4 : 9;
    int coff = c9 << 2;
    int ncv  = nc[row];                    // wave-uniform
    size_t base = (size_t)row * CAP_ + grp;
    f32x4 acc = {0.f, 0.f, 0.f, 0.f};
    for (int c = 0; c < ncv; ++c) {
        size_t i = base + (size_t)c * 16;
        unsigned int q0 = pw[i];
        unsigned int q1 = pw[i + 4];
        unsigned int q2 = pw[i + 8];
        unsigned int q3 = pw[i + 12];
        f32x4 g0 = *(const f32x4*)(zin + (size_t)(q0 & 0x1FFFu) * C_ + coff);
        f32x4 g1 = *(const f32x4*)(zin + (size_t)(q1 & 0x1FFFu) * C_ + coff);
        f32x4 g2 = *(const f32x4*)(zin + (size_t)(q2 & 0x1FFFu) * C_ + coff);
        f32x4 g3 = *(const f32x4*)(zin + (size_t)(q3 & 0x1FFFu) * C_ + coff);
        float w0 = __uint_as_float(q0 & 0xFFFFE000u);
        float w1 = __uint_as_float(q1 & 0xFFFFE000u);
        float w2 = __uint_as_float(q2 & 0xFFFFE000u);
        float w3 = __uint_as_float(q3 & 0xFFFFE000u);
        acc[0] = fmaf(w0, g0[0], acc[0]); acc[1] = fmaf(w0, g0[1], acc[1]);
        acc[2] = fmaf(w0, g0[2], acc[2]); acc[3] = fmaf(w0, g0[3], acc[3]);
        acc[0] = fmaf(w1, g1[0], acc[0]); acc[1] = fmaf(w1, g1[1], acc[1]);
        acc[2] = fmaf(w1, g1[2], acc[2]); acc[3] = fmaf(w1, g1[3], acc[3]);
        acc[0] = fmaf(w2, g2[0], acc[0]); acc[1] = fmaf(w2, g2[1], acc[1]);
        acc[2] = fmaf(w2, g2[2], acc[2]); acc[3] = fmaf(w2, g2[3], acc[3]);
        acc[0] = fmaf(w3, g3[0], acc[0]); acc[1] = fmaf(w3, g3[1], acc[1]);
        acc[2] = fmaf(w3, g3[2], acc[2]); acc[3] = fmaf(w3, g3[3], acc[3]);
    }
    acc[0] += __shfl_xor(acc[0], 16); acc[1] += __shfl_xor(acc[1], 16);
    acc[2] += __shfl_xor(acc[2], 16); acc[3] += __shfl_xor(acc[3], 16);
    acc[0] += __shfl_xor(acc[0], 32); acc[1] += __shfl_xor(acc[1], 32);
    acc[2] += __shfl_xor(acc[2], 32); acc[3] += __shfl_xor(acc[3], 32);
    if (grp == 0 && col4 < 10) {
        f32x4 xr = *(const f32x4*)(zin + (size_t)row * C_ + (col4 << 2));
        f32x4 r;
        r[0] = fmaf(1.0f - TAU_, xr[0], acc[0]);
        r[1] = fmaf(1.0f - TAU_, xr[1], acc[1]);
        r[2] = fmaf(1.0f - TAU_, xr[2], acc[2]);
        r[3] = fmaf(1.0f - TAU_, xr[3], acc[3]);
        if (LAST) {
            f32x4 bb = *(const f32x4*)(db + (col4 << 2));
            r[0] += bb[0]; r[1] += bb[1]; r[2] += bb[2]; r[3] += bb[3];
        }
        *(f32x4*)(zout + (size_t)row * C_ + (col4 << 2)) = r;
    }
}

extern "C" void kernel_launch(void* const* d_in, const int* in_sizes, int n_in,
                              void* d_out, int out_size, void* d_ws, size_t ws_size,
                              hipStream_t stream)
{
    const float* x_in  = (const float*)d_in[0];
    const float* enc_w = (const float*)d_in[1];
    const float* enc_b = (const float*)d_in[2];
    const float* wk_w  = (const float*)d_in[3];
    const float* wk_b  = (const float*)d_in[4];
    const float* wq_w  = (const float*)d_in[5];
    const float* wq_b  = (const float*)d_in[6];
    const float* dec_w = (const float*)d_in[7];
    const float* dec_b = (const float*)d_in[8];
    const int2*  edges = (const int2*)d_in[9];
    const int E = in_sizes[9] / 2;   // 262144
    float* out = (float*)d_out;

    char* ws = (char*)d_ws;
    float*        za   = (float*)(ws + 0);                    // 1.31 MB (+pad)
    float*        zb   = (float*)(ws + (2u << 20));           // 1.31 MB (+pad)
    float*        kx   = (float*)(ws + (4u << 20));           // 2 MB
    float*        qx   = (float*)(ws + (6u << 20));           // 2 MB
    int2*         bvw  = (int2*) (ws + (8u << 20));           // 8 MB raw buckets
    unsigned int* pw   = (unsigned int*)(ws + (16u << 20));   // 4 MB packed
    int*          fill = (int*)  (ws + (20u << 20));          // 32 KB
    int*          nc   = (int*)  (ws + (20u << 20) + (64u << 10)); // 32 KB

    hipMemsetAsync(fill, 0, N_ * sizeof(int), stream);

    front_k<<<N_ / 16, 256, 0, stream>>>(x_in, enc_w, enc_b, wk_w, wk_b,
                                         wq_w, wq_b, dec_w, kx, qx, za);
    score_place_k<<<(E * 8 + 255) / 256, 256, 0, stream>>>(edges, kx, qx, fill, bvw, E);
    dedup_k<<<N_ / 4, 256, 0, stream>>>(fill, bvw, pw, nc);

    float* zi = za;
    for (int s = 0; s < STEPS_ - 1; ++s) {
        stepz_k<false><<<N_ / 4, 256, 0, stream>>>(zi, (zi == za) ? zb : za,
                                                   nc, pw, dec_b);
        zi = (zi == za) ? zb : za;
    }
    stepz_k<true><<<N_ / 4, 256, 0, stream>>>(zi, out, nc, pw, dec_b);
}

// Round 11
// 165.924 us; speedup vs baseline: 1.3835x; 1.0005x over previous
//
#include <hip/hip_runtime.h>
#include <hip/hip_bf16.h>

// N=8192, D_IN=128, H=64, C=40, E=262144, TAU=0.25, T=4 -> 16 steps.
constexpr int N_   = 8192;
constexpr int DIN_ = 128;
constexpr int H_   = 64;
constexpr int C_   = 40;
constexpr int STEPS_ = 16;
constexpr int CAP_ = 128;            // row bucket capacity (max raw deg ~65)
#define TAU_ 0.25f

typedef float f32x4 __attribute__((ext_vector_type(4)));
typedef unsigned int u32x4 __attribute__((ext_vector_type(4)));

// pack (v, w) -> 4B: high 19 bits = fp32 w RNE-rounded to 10-bit mantissa,
// low 13 bits = v. w >= 0 always; w=0 packs/decodes exactly (packvw(0,0)==0).
__device__ __forceinline__ unsigned int packvw(int v, float w)
{
    unsigned int u = __float_as_uint(w);
    u += 0x0FFFu + ((u >> 13) & 1u);     // round-to-nearest-even at bit 13
    u &= 0xFFFFE000u;
    return u | (unsigned int)v;
}

// ---------------- fused front-end: enc + kq + z0 = x0 @ dec_w ---------------
__global__ __launch_bounds__(256) void front_k(const float* __restrict__ xin,
    const float* __restrict__ ew, const float* __restrict__ eb,
    const float* __restrict__ wk, const float* __restrict__ kb,
    const float* __restrict__ wq, const float* __restrict__ qb,
    const float* __restrict__ dw,
    float* __restrict__ kx, float* __restrict__ qx, float* __restrict__ z0)
{
    __shared__ float xs[16][64];                 // 4 waves x 4 rows
    int wloc = threadIdx.x >> 6;
    int lane = threadIdx.x & 63;
    int r0   = (blockIdx.x * 4 + wloc) * 4;

    const float* xr = xin + (size_t)r0 * DIN_;
    float bv = eb[lane];
    float a0 = bv, a1 = bv, a2 = bv, a3 = bv;
    for (int k = 0; k < DIN_; ++k) {
        float wv = ew[k * H_ + lane];
        a0 = fmaf(xr[k],            wv, a0);
        a1 = fmaf(xr[DIN_ + k],     wv, a1);
        a2 = fmaf(xr[2 * DIN_ + k], wv, a2);
        a3 = fmaf(xr[3 * DIN_ + k], wv, a3);
    }
    float* xls = &xs[wloc * 4][0];
    xls[lane] = a0; xls[64 + lane] = a1; xls[128 + lane] = a2; xls[192 + lane] = a3;

    float kbv = kb[lane], qbv = qb[lane];
    float ak0 = kbv, ak1 = kbv, ak2 = kbv, ak3 = kbv;
    float aq0 = qbv, aq1 = qbv, aq2 = qbv, aq3 = qbv;
    for (int k = 0; k < H_; ++k) {
        float wkv = wk[k * H_ + lane];
        float wqv = wq[k * H_ + lane];
        float x0v = xls[k], x1v = xls[64 + k], x2v = xls[128 + k], x3v = xls[192 + k];
        ak0 = fmaf(x0v, wkv, ak0);  aq0 = fmaf(x0v, wqv, aq0);
        ak1 = fmaf(x1v, wkv, ak1);  aq1 = fmaf(x1v, wqv, aq1);
        ak2 = fmaf(x2v, wkv, ak2);  aq2 = fmaf(x2v, wqv, aq2);
        ak3 = fmaf(x3v, wkv, ak3);  aq3 = fmaf(x3v, wqv, aq3);
    }
    float* ok = kx + (size_t)r0 * H_ + lane;
    float* oq = qx + (size_t)r0 * H_ + lane;
    ok[0] = ak0; ok[H_] = ak1; ok[2 * H_] = ak2; ok[3 * H_] = ak3;
    oq[0] = aq0; oq[H_] = aq1; oq[2 * H_] = aq2; oq[3 * H_] = aq3;

    if (lane < C_) {
        float z0a = 0.f, z1a = 0.f, z2a = 0.f, z3a = 0.f;
        for (int k = 0; k < H_; ++k) {
            float dv = dw[k * C_ + lane];
            z0a = fmaf(xls[k],       dv, z0a);
            z1a = fmaf(xls[64 + k],  dv, z1a);
            z2a = fmaf(xls[128 + k], dv, z2a);
            z3a = fmaf(xls[192 + k], dv, z3a);
        }
        z0[(size_t)r0 * C_ + lane]       = z0a;
        z0[(size_t)(r0 + 1) * C_ + lane] = z1a;
        z0[(size_t)(r0 + 2) * C_ + lane] = z2a;
        z0[(size_t)(r0 + 3) * C_ + lane] = z3a;
    }
}

// ---------------- edge scoring straight into padded row buckets -------------
__global__ __launch_bounds__(256) void score_place_k(const int2* __restrict__ edges,
    const float* __restrict__ kx, const float* __restrict__ qx,
    int* __restrict__ fill, int2* __restrict__ bvw, int E)
{
    int t  = blockIdx.x * 256 + threadIdx.x;
    int eg = t >> 3;
    int sl = t & 7;
    if (eg >= E) return;
    int2 uv = edges[eg];
    const float4* kr = (const float4*)(kx + (size_t)uv.x * H_);
    const float4* qr = (const float4*)(qx + (size_t)uv.y * H_);
    float4 a0 = kr[sl], a1 = kr[sl + 8];
    float4 b0 = qr[sl], b1 = qr[sl + 8];
    float d = a0.x * b0.x + a0.y * b0.y + a0.z * b0.z + a0.w * b0.w
            + a1.x * b1.x + a1.y * b1.y + a1.z * b1.z + a1.w * b1.w;
    d += __shfl_xor(d, 1);
    d += __shfl_xor(d, 2);
    d += __shfl_xor(d, 4);
    if (sl == 0) {
        float w = expf(d * (1.0f / (float)H_));
        int pos = atomicAdd(&fill[uv.x], 1);
        if (pos < CAP_)
            bvw[(size_t)uv.x * CAP_ + pos] = make_int2(uv.y, __float_as_int(w));
    }
}

// ---------------- per-row dedup + normalize + pack (single pass) ------------
// Wave per row; lane owns slots {lane, lane+64}. LDS bitmap dedup (any-winner
// exact). Packed 4B (v,w) written to INTERLEAVED layout: original slot
// p = c*16 + grp + 4*jj  ->  newp = c*16 + grp*4 + jj, so each stepz group's
// 4 edge-packets are one contiguous 16B quad. Permutation is within-chunk
// (same 64B line). Padding packs to 0 -> w=0.
__global__ __launch_bounds__(256) void dedup_k(const int* __restrict__ fill,
    const int2* __restrict__ bvw, unsigned int* __restrict__ pw,
    int* __restrict__ nc)
{
    __shared__ unsigned int bm[4][256];   // 8192 bits per wave
    int wv   = threadIdx.x >> 6;
    int lane = threadIdx.x & 63;
    int row  = blockIdx.x * 4 + wv;
    unsigned int* b = bm[wv];
    for (int i = lane; i < 256; i += 64) b[i] = 0;
    __syncthreads();
    int f = fill[row];
    if (f > CAP_) f = CAP_;
    int padded = (f + 15) & ~15;
    size_t base = (size_t)row * CAP_;
    int2 ea = make_int2(0, 0), eb = make_int2(0, 0);
    float wa = 0.f, wb = 0.f;
    if (lane < f) {
        ea = bvw[base + lane];
        unsigned int m = 1u << (ea.x & 31);
        unsigned int old = atomicOr(&b[ea.x >> 5], m);
        wa = (old & m) ? 0.0f : __int_as_float(ea.y);
    }
    if (64 + lane < f) {
        eb = bvw[base + 64 + lane];
        unsigned int m = 1u << (eb.x & 31);
        unsigned int old = atomicOr(&b[eb.x >> 5], m);
        wb = (old & m) ? 0.0f : __int_as_float(eb.y);
    }
    float wsum = wa + wb;
    #pragma unroll
    for (int off = 1; off < 64; off <<= 1) wsum += __shfl_xor(wsum, off);
    if (lane == 0) nc[row] = padded >> 4;
    if (f == 0) return;
    float scale = TAU_ / wsum;
    // interleave permutation: newp = (p & ~15) | ((p & 3) << 2) | ((p & 15) >> 2)
    int pa = lane;
    int na = (pa & ~15) | ((pa & 3) << 2) | ((pa & 15) >> 2);
    int pb = 64 + lane;
    int nb = (pb & ~15) | ((pb & 3) << 2) | ((pb & 15) >> 2);
    if (pa < padded) pw[base + na] = packvw(ea.x, wa * scale);
    if (pb < padded) pw[base + nb] = packvw(eb.x, wb * scale);
}

// ---------------- propagation step over z (N x 40) ----------------
// Wave = row. Lane L: edge-group grp=L>>4, float4-col c=L&15 (c<10 valid,
// c>=10 clamps to col 9 -> requests merge). Per chunk: ONE dwordx4 pw quad
// (4 edges), 4 dwordx4 z-gathers, 16 fma. Next chunk's quad is loaded after
// the gathers issue (software lookahead) so its latency hides under them.
template <bool LAST>
__global__ __launch_bounds__(256) void stepz_k(const float* __restrict__ zin,
    float* __restrict__ zout, const int* __restrict__ nc,
    const unsigned int* __restrict__ pw, const float* __restrict__ db)
{
    int row  = (blockIdx.x * 256 + threadIdx.x) >> 6;
    int lane = threadIdx.x & 63;
    int grp  = lane >> 4;
    int col4 = lane & 15;
    int c9   = (col4 < 10) ? col4 : 9;
    int coff = c9 << 2;
    int ncv  = nc[row];                    // wave-uniform
    const unsigned int* pwrow = pw + (size_t)row * CAP_ + (grp << 2);
    f32x4 acc = {0.f, 0.f, 0.f, 0.f};
    u32x4 q = *(const u32x4*)pwrow;        // chunk 0 quad (unused if ncv==0)
    for (int c = 0; c < ncv; ++c) {
        f32x4 g0 = *(const f32x4*)(zin + (size_t)(q[0] & 0x1FFFu) * C_ + coff);
        f32x4 g1 = *(const f32x4*)(zin + (size_t)(q[1] & 0x1FFFu) * C_ + coff);
        f32x4 g2 = *(const f32x4*)(zin + (size_t)(q[2] & 0x1FFFu) * C_ + coff);
        f32x4 g3 = *(const f32x4*)(zin + (size_t)(q[3] & 0x1FFFu) * C_ + coff);
        int cn = (c + 1 < ncv) ? (c + 1) : c;            // branch-free lookahead
        u32x4 qn = *(const u32x4*)(pwrow + ((size_t)cn << 4));
        float w0 = __uint_as_float(q[0] & 0xFFFFE000u);
        float w1 = __uint_as_float(q[1] & 0xFFFFE000u);
        float w2 = __uint_as_float(q[2] & 0xFFFFE000u);
        float w3 = __uint_as_float(q[3] & 0xFFFFE000u);
        acc[0] = fmaf(w0, g0[0], acc[0]); acc[1] = fmaf(w0, g0[1], acc[1]);
        acc[2] = fmaf(w0, g0[2], acc[2]); acc[3] = fmaf(w0, g0[3], acc[3]);
        acc[0] = fmaf(w1, g1[0], acc[0]); acc[1] = fmaf(w1, g1[1], acc[1]);
        acc[2] = fmaf(w1, g1[2], acc[2]); acc[3] = fmaf(w1, g1[3], acc[3]);
        acc[0] = fmaf(w2, g2[0], acc[0]); acc[1] = fmaf(w2, g2[1], acc[1]);
        acc[2] = fmaf(w2, g2[2], acc[2]); acc[3] = fmaf(w2, g2[3], acc[3]);
        acc[0] = fmaf(w3, g3[0], acc[0]); acc[1] = fmaf(w3, g3[1], acc[1]);
        acc[2] = fmaf(w3, g3[2], acc[2]); acc[3] = fmaf(w3, g3[3], acc[3]);
        q = qn;
    }
    acc[0] += __shfl_xor(acc[0], 16); acc[1] += __shfl_xor(acc[1], 16);
    acc[2] += __shfl_xor(acc[2], 16); acc[3] += __shfl_xor(acc[3], 16);
    acc[0] += __shfl_xor(acc[0], 32); acc[1] += __shfl_xor(acc[1], 32);
    acc[2] += __shfl_xor(acc[2], 32); acc[3] += __shfl_xor(acc[3], 32);
    if (grp == 0 && col4 < 10) {
        f32x4 xr = *(const f32x4*)(zin + (size_t)row * C_ + (col4 << 2));
        f32x4 r;
        r[0] = fmaf(1.0f - TAU_, xr[0], acc[0]);
        r[1] = fmaf(1.0f - TAU_, xr[1], acc[1]);
        r[2] = fmaf(1.0f - TAU_, xr[2], acc[2]);
        r[3] = fmaf(1.0f - TAU_, xr[3], acc[3]);
        if (LAST) {
            f32x4 bb = *(const f32x4*)(db + (col4 << 2));
            r[0] += bb[0]; r[1] += bb[1]; r[2] += bb[2]; r[3] += bb[3];
        }
        *(f32x4*)(zout + (size_t)row * C_ + (col4 << 2)) = r;
    }
}

extern "C" void kernel_launch(void* const* d_in, const int* in_sizes, int n_in,
                              void* d_out, int out_size, void* d_ws, size_t ws_size,
                              hipStream_t stream)
{
    const float* x_in  = (const float*)d_in[0];
    const float* enc_w = (const float*)d_in[1];
    const float* enc_b = (const float*)d_in[2];
    const float* wk_w  = (const float*)d_in[3];
    const float* wk_b  = (const float*)d_in[4];
    const float* wq_w  = (const float*)d_in[5];
    const float* wq_b  = (const float*)d_in[6];
    const float* dec_w = (const float*)d_in[7];
    const float* dec_b = (const float*)d_in[8];
    const int2*  edges = (const int2*)d_in[9];
    const int E = in_sizes[9] / 2;   // 262144
    float* out = (float*)d_out;

    char* ws = (char*)d_ws;
    float*        za   = (float*)(ws + 0);                    // 1.31 MB (+pad)
    float*        zb   = (float*)(ws + (2u << 20));           // 1.31 MB (+pad)
    float*        kx   = (float*)(ws + (4u << 20));           // 2 MB
    float*        qx   = (float*)(ws + (6u << 20));           // 2 MB
    int2*         bvw  = (int2*) (ws + (8u << 20));           // 8 MB raw buckets
    unsigned int* pw   = (unsigned int*)(ws + (16u << 20));   // 4 MB packed
    int*          fill = (int*)  (ws + (20u << 20));          // 32 KB
    int*          nc   = (int*)  (ws + (20u << 20) + (64u << 10)); // 32 KB

    hipMemsetAsync(fill, 0, N_ * sizeof(int), stream);

    front_k<<<N_ / 16, 256, 0, stream>>>(x_in, enc_w, enc_b, wk_w, wk_b,
                                         wq_w, wq_b, dec_w, kx, qx, za);
    score_place_k<<<(E * 8 + 255) / 256, 256, 0, stream>>>(edges, kx, qx, fill, bvw, E);
    dedup_k<<<N_ / 4, 256, 0, stream>>>(fill, bvw, pw, nc);

    float* zi = za;
    for (int s = 0; s < STEPS_ - 1; ++s) {
        stepz_k<false><<<N_ / 4, 256, 0, stream>>>(zi, (zi == za) ? zb : za,
                                                   nc, pw, dec_b);
        zi = (zi == za) ? zb : za;
    }
    stepz_k<true><<<N_ / 4, 256, 0, stream>>>(zi, out, nc, pw, dec_b);
}

// Round 12
// 153.504 us; speedup vs baseline: 1.4954x; 1.0809x over previous
//
#include <hip/hip_runtime.h>
#include <hip/hip_bf16.h>

// N=8192, D_IN=128, H=64, C=40, E=262144, TAU=0.25, T=4 -> 16 steps.
constexpr int N_   = 8192;
constexpr int DIN_ = 128;
constexpr int H_   = 64;
constexpr int C_   = 40;
constexpr int STEPS_ = 16;
constexpr int CAP_ = 128;            // row bucket capacity (max raw deg ~65)
#define TAU_ 0.25f

typedef float    f32x4 __attribute__((ext_vector_type(4)));
typedef unsigned int u32x4 __attribute__((ext_vector_type(4)));
typedef _Float16 f16x4 __attribute__((ext_vector_type(4)));

// pack (v, w) -> 4B: high 19 bits = fp32 w RNE-rounded to 10-bit mantissa,
// low 13 bits = v. w >= 0 always; w=0 packs/decodes exactly (packvw(0,0)==0).
__device__ __forceinline__ unsigned int packvw(int v, float w)
{
    unsigned int u = __float_as_uint(w);
    u += 0x0FFFu + ((u >> 13) & 1u);     // round-to-nearest-even at bit 13
    u &= 0xFFFFE000u;
    return u | (unsigned int)v;
}

// ---------------- fused front-end: enc + kq + z0 = x0 @ dec_w ---------------
__global__ __launch_bounds__(256) void front_k(const float* __restrict__ xin,
    const float* __restrict__ ew, const float* __restrict__ eb,
    const float* __restrict__ wk, const float* __restrict__ kb,
    const float* __restrict__ wq, const float* __restrict__ qb,
    const float* __restrict__ dw,
    float* __restrict__ kx, float* __restrict__ qx,
    float* __restrict__ z0, _Float16* __restrict__ zh0)
{
    __shared__ float xs[16][64];                 // 4 waves x 4 rows
    int wloc = threadIdx.x >> 6;
    int lane = threadIdx.x & 63;
    int r0   = (blockIdx.x * 4 + wloc) * 4;

    const float* xr = xin + (size_t)r0 * DIN_;
    float bv = eb[lane];
    float a0 = bv, a1 = bv, a2 = bv, a3 = bv;
    for (int k = 0; k < DIN_; ++k) {
        float wv = ew[k * H_ + lane];
        a0 = fmaf(xr[k],            wv, a0);
        a1 = fmaf(xr[DIN_ + k],     wv, a1);
        a2 = fmaf(xr[2 * DIN_ + k], wv, a2);
        a3 = fmaf(xr[3 * DIN_ + k], wv, a3);
    }
    float* xls = &xs[wloc * 4][0];
    xls[lane] = a0; xls[64 + lane] = a1; xls[128 + lane] = a2; xls[192 + lane] = a3;

    float kbv = kb[lane], qbv = qb[lane];
    float ak0 = kbv, ak1 = kbv, ak2 = kbv, ak3 = kbv;
    float aq0 = qbv, aq1 = qbv, aq2 = qbv, aq3 = qbv;
    for (int k = 0; k < H_; ++k) {
        float wkv = wk[k * H_ + lane];
        float wqv = wq[k * H_ + lane];
        float x0v = xls[k], x1v = xls[64 + k], x2v = xls[128 + k], x3v = xls[192 + k];
        ak0 = fmaf(x0v, wkv, ak0);  aq0 = fmaf(x0v, wqv, aq0);
        ak1 = fmaf(x1v, wkv, ak1);  aq1 = fmaf(x1v, wqv, aq1);
        ak2 = fmaf(x2v, wkv, ak2);  aq2 = fmaf(x2v, wqv, aq2);
        ak3 = fmaf(x3v, wkv, ak3);  aq3 = fmaf(x3v, wqv, aq3);
    }
    float* ok = kx + (size_t)r0 * H_ + lane;
    float* oq = qx + (size_t)r0 * H_ + lane;
    ok[0] = ak0; ok[H_] = ak1; ok[2 * H_] = ak2; ok[3 * H_] = ak3;
    oq[0] = aq0; oq[H_] = aq1; oq[2 * H_] = aq2; oq[3 * H_] = aq3;

    if (lane < C_) {
        float z0a = 0.f, z1a = 0.f, z2a = 0.f, z3a = 0.f;
        for (int k = 0; k < H_; ++k) {
            float dv = dw[k * C_ + lane];
            z0a = fmaf(xls[k],       dv, z0a);
            z1a = fmaf(xls[64 + k],  dv, z1a);
            z2a = fmaf(xls[128 + k], dv, z2a);
            z3a = fmaf(xls[192 + k], dv, z3a);
        }
        z0[(size_t)r0 * C_ + lane]       = z0a;
        z0[(size_t)(r0 + 1) * C_ + lane] = z1a;
        z0[(size_t)(r0 + 2) * C_ + lane] = z2a;
        z0[(size_t)(r0 + 3) * C_ + lane] = z3a;
        zh0[(size_t)r0 * C_ + lane]       = (_Float16)z0a;
        zh0[(size_t)(r0 + 1) * C_ + lane] = (_Float16)z1a;
        zh0[(size_t)(r0 + 2) * C_ + lane] = (_Float16)z2a;
        zh0[(size_t)(r0 + 3) * C_ + lane] = (_Float16)z3a;
    }
}

// ---------------- edge scoring straight into padded row buckets -------------
__global__ __launch_bounds__(256) void score_place_k(const int2* __restrict__ edges,
    const float* __restrict__ kx, const float* __restrict__ qx,
    int* __restrict__ fill, int2* __restrict__ bvw, int E)
{
    int t  = blockIdx.x * 256 + threadIdx.x;
    int eg = t >> 3;
    int sl = t & 7;
    if (eg >= E) return;
    int2 uv = edges[eg];
    const float4* kr = (const float4*)(kx + (size_t)uv.x * H_);
    const float4* qr = (const float4*)(qx + (size_t)uv.y * H_);
    float4 a0 = kr[sl], a1 = kr[sl + 8];
    float4 b0 = qr[sl], b1 = qr[sl + 8];
    float d = a0.x * b0.x + a0.y * b0.y + a0.z * b0.z + a0.w * b0.w
            + a1.x * b1.x + a1.y * b1.y + a1.z * b1.z + a1.w * b1.w;
    d += __shfl_xor(d, 1);
    d += __shfl_xor(d, 2);
    d += __shfl_xor(d, 4);
    if (sl == 0) {
        float w = expf(d * (1.0f / (float)H_));
        int pos = atomicAdd(&fill[uv.x], 1);
        if (pos < CAP_)
            bvw[(size_t)uv.x * CAP_ + pos] = make_int2(uv.y, __float_as_int(w));
    }
}

// ---------------- per-row dedup + normalize + pack (single pass) ------------
__global__ __launch_bounds__(256) void dedup_k(const int* __restrict__ fill,
    const int2* __restrict__ bvw, unsigned int* __restrict__ pw,
    int* __restrict__ nc)
{
    __shared__ unsigned int bm[4][256];   // 8192 bits per wave
    int wv   = threadIdx.x >> 6;
    int lane = threadIdx.x & 63;
    int row  = blockIdx.x * 4 + wv;
    unsigned int* b = bm[wv];
    for (int i = lane; i < 256; i += 64) b[i] = 0;
    __syncthreads();
    int f = fill[row];
    if (f > CAP_) f = CAP_;
    int padded = (f + 15) & ~15;
    size_t base = (size_t)row * CAP_;
    int2 ea = make_int2(0, 0), eb = make_int2(0, 0);
    float wa = 0.f, wb = 0.f;
    if (lane < f) {
        ea = bvw[base + lane];
        unsigned int m = 1u << (ea.x & 31);
        unsigned int old = atomicOr(&b[ea.x >> 5], m);
        wa = (old & m) ? 0.0f : __int_as_float(ea.y);
    }
    if (64 + lane < f) {
        eb = bvw[base + 64 + lane];
        unsigned int m = 1u << (eb.x & 31);
        unsigned int old = atomicOr(&b[eb.x >> 5], m);
        wb = (old & m) ? 0.0f : __int_as_float(eb.y);
    }
    float wsum = wa + wb;
    #pragma unroll
    for (int off = 1; off < 64; off <<= 1) wsum += __shfl_xor(wsum, off);
    if (lane == 0) nc[row] = padded >> 4;
    if (f == 0) return;
    float scale = TAU_ / wsum;
    // interleave permutation: newp = (p & ~15) | ((p & 3) << 2) | ((p & 15) >> 2)
    int pa = lane;
    int na = (pa & ~15) | ((pa & 3) << 2) | ((pa & 15) >> 2);
    int pb = 64 + lane;
    int nb = (pb & ~15) | ((pb & 3) << 2) | ((pb & 15) >> 2);
    if (pa < padded) pw[base + na] = packvw(ea.x, wa * scale);
    if (pb < padded) pw[base + nb] = packvw(eb.x, wb * scale);
}

// ---------------- propagation step over z (N x 40) ----------------
// State z stays fp32 (diagonal term + output exact); gathers read the fp16
// shadow zh (80 B/row -> ~40% fewer 64B-line requests). Wave = row; grp=L>>4,
// col4=L&15 (c<10 valid). Per chunk: one dwordx4 pw quad + 4 dwordx2 fp16
// gathers + converts + 16 fma. Writes fp32 y and fp16 yh (except LAST: fp32
// out only).
template <bool LAST>
__global__ __launch_bounds__(256) void stepz_k(const float* __restrict__ zin,
    const _Float16* __restrict__ zhin, float* __restrict__ zout,
    _Float16* __restrict__ zhout, const int* __restrict__ nc,
    const unsigned int* __restrict__ pw, const float* __restrict__ db)
{
    int row  = (blockIdx.x * 256 + threadIdx.x) >> 6;
    int lane = threadIdx.x & 63;
    int grp  = lane >> 4;
    int col4 = lane & 15;
    int c9   = (col4 < 10) ? col4 : 9;
    int ch   = c9 << 2;                    // half-offset within row
    int ncv  = nc[row];                    // wave-uniform
    const unsigned int* pwrow = pw + (size_t)row * CAP_ + (grp << 2);
    f32x4 acc = {0.f, 0.f, 0.f, 0.f};
    u32x4 q = *(const u32x4*)pwrow;        // chunk 0 quad (unused if ncv==0)
    for (int c = 0; c < ncv; ++c) {
        f16x4 h0 = *(const f16x4*)(zhin + (size_t)(q[0] & 0x1FFFu) * C_ + ch);
        f16x4 h1 = *(const f16x4*)(zhin + (size_t)(q[1] & 0x1FFFu) * C_ + ch);
        f16x4 h2 = *(const f16x4*)(zhin + (size_t)(q[2] & 0x1FFFu) * C_ + ch);
        f16x4 h3 = *(const f16x4*)(zhin + (size_t)(q[3] & 0x1FFFu) * C_ + ch);
        int cn = (c + 1 < ncv) ? (c + 1) : c;            // branch-free lookahead
        u32x4 qn = *(const u32x4*)(pwrow + ((size_t)cn << 4));
        float w0 = __uint_as_float(q[0] & 0xFFFFE000u);
        float w1 = __uint_as_float(q[1] & 0xFFFFE000u);
        float w2 = __uint_as_float(q[2] & 0xFFFFE000u);
        float w3 = __uint_as_float(q[3] & 0xFFFFE000u);
        acc[0] = fmaf(w0, (float)h0[0], acc[0]); acc[1] = fmaf(w0, (float)h0[1], acc[1]);
        acc[2] = fmaf(w0, (float)h0[2], acc[2]); acc[3] = fmaf(w0, (float)h0[3], acc[3]);
        acc[0] = fmaf(w1, (float)h1[0], acc[0]); acc[1] = fmaf(w1, (float)h1[1], acc[1]);
        acc[2] = fmaf(w1, (float)h1[2], acc[2]); acc[3] = fmaf(w1, (float)h1[3], acc[3]);
        acc[0] = fmaf(w2, (float)h2[0], acc[0]); acc[1] = fmaf(w2, (float)h2[1], acc[1]);
        acc[2] = fmaf(w2, (float)h2[2], acc[2]); acc[3] = fmaf(w2, (float)h2[3], acc[3]);
        acc[0] = fmaf(w3, (float)h3[0], acc[0]); acc[1] = fmaf(w3, (float)h3[1], acc[1]);
        acc[2] = fmaf(w3, (float)h3[2], acc[2]); acc[3] = fmaf(w3, (float)h3[3], acc[3]);
        q = qn;
    }
    acc[0] += __shfl_xor(acc[0], 16); acc[1] += __shfl_xor(acc[1], 16);
    acc[2] += __shfl_xor(acc[2], 16); acc[3] += __shfl_xor(acc[3], 16);
    acc[0] += __shfl_xor(acc[0], 32); acc[1] += __shfl_xor(acc[1], 32);
    acc[2] += __shfl_xor(acc[2], 32); acc[3] += __shfl_xor(acc[3], 32);
    if (grp == 0 && col4 < 10) {
        f32x4 xr = *(const f32x4*)(zin + (size_t)row * C_ + (col4 << 2));
        f32x4 r;
        r[0] = fmaf(1.0f - TAU_, xr[0], acc[0]);
        r[1] = fmaf(1.0f - TAU_, xr[1], acc[1]);
        r[2] = fmaf(1.0f - TAU_, xr[2], acc[2]);
        r[3] = fmaf(1.0f - TAU_, xr[3], acc[3]);
        if (LAST) {
            f32x4 bb = *(const f32x4*)(db + (col4 << 2));
            r[0] += bb[0]; r[1] += bb[1]; r[2] += bb[2]; r[3] += bb[3];
        }
        *(f32x4*)(zout + (size_t)row * C_ + (col4 << 2)) = r;
        if (!LAST) {
            f16x4 rh;
            rh[0] = (_Float16)r[0]; rh[1] = (_Float16)r[1];
            rh[2] = (_Float16)r[2]; rh[3] = (_Float16)r[3];
            *(f16x4*)(zhout + (size_t)row * C_ + (col4 << 2)) = rh;
        }
    }
}

extern "C" void kernel_launch(void* const* d_in, const int* in_sizes, int n_in,
                              void* d_out, int out_size, void* d_ws, size_t ws_size,
                              hipStream_t stream)
{
    const float* x_in  = (const float*)d_in[0];
    const float* enc_w = (const float*)d_in[1];
    const float* enc_b = (const float*)d_in[2];
    const float* wk_w  = (const float*)d_in[3];
    const float* wk_b  = (const float*)d_in[4];
    const float* wq_w  = (const float*)d_in[5];
    const float* wq_b  = (const float*)d_in[6];
    const float* dec_w = (const float*)d_in[7];
    const float* dec_b = (const float*)d_in[8];
    const int2*  edges = (const int2*)d_in[9];
    const int E = in_sizes[9] / 2;   // 262144
    float* out = (float*)d_out;

    char* ws = (char*)d_ws;
    float*        za   = (float*)(ws + 0);                    // 1.31 MB (+pad)
    float*        zb   = (float*)(ws + (2u << 20));           // 1.31 MB (+pad)
    float*        kx   = (float*)(ws + (4u << 20));           // 2 MB
    float*        qx   = (float*)(ws + (6u << 20));           // 2 MB
    int2*         bvw  = (int2*) (ws + (8u << 20));           // 8 MB raw buckets
    unsigned int* pw   = (unsigned int*)(ws + (16u << 20));   // 4 MB packed
    int*          fill = (int*)  (ws + (20u << 20));          // 32 KB
    int*          nc   = (int*)  (ws + (20u << 20) + (64u << 10)); // 32 KB
    _Float16*     zha  = (_Float16*)(ws + (21u << 20));       // 640 KB
    _Float16*     zhb  = (_Float16*)(ws + (22u << 20));       // 640 KB

    hipMemsetAsync(fill, 0, N_ * sizeof(int), stream);

    front_k<<<N_ / 16, 256, 0, stream>>>(x_in, enc_w, enc_b, wk_w, wk_b,
                                         wq_w, wq_b, dec_w, kx, qx, za, zha);
    score_place_k<<<(E * 8 + 255) / 256, 256, 0, stream>>>(edges, kx, qx, fill, bvw, E);
    dedup_k<<<N_ / 4, 256, 0, stream>>>(fill, bvw, pw, nc);

    float*    zi  = za;
    _Float16* zhi = zha;
    for (int s = 0; s < STEPS_ - 1; ++s) {
        float*    zo  = (zi == za) ? zb : za;
        _Float16* zho = (zhi == zha) ? zhb : zha;
        stepz_k<false><<<N_ / 4, 256, 0, stream>>>(zi, zhi, zo, zho, nc, pw, dec_b);
        zi = zo; zhi = zho;
    }
    stepz_k<true><<<N_ / 4, 256, 0, stream>>>(zi, zhi, out, nullptr, nc, pw, dec_b);
}